// Round 11
// baseline (147.645 us; speedup 1.0000x reference)
//
#include <hip/hip_runtime.h>
#include <hip/hip_bf16.h>
#include <math.h>

#define N_ATOMS 10000
#define N_PAIRS 160000
#define FDIM 256
#define GDIM 16
#define HDIM 64
#define HIDDIM 256
#define MLP_IN 640
#define MLP_OUT 258

typedef __attribute__((ext_vector_type(8))) short short8;
typedef __attribute__((ext_vector_type(4))) float f32x4;

__device__ __forceinline__ float gelu_exact(float x) {
    return 0.5f * x * (1.0f + erff(x * 0.70710678118654752f));
}
__device__ __forceinline__ short bf16bits(float x) {
    __hip_bfloat16 h = __float2bfloat16(x);
    return *reinterpret_cast<short*>(&h);
}
__device__ __forceinline__ short8 cvt8(f32x4 v0, f32x4 v1) {
    short8 o;
    o[0] = bf16bits(v0[0]); o[1] = bf16bits(v0[1]);
    o[2] = bf16bits(v0[2]); o[3] = bf16bits(v0[3]);
    o[4] = bf16bits(v1[0]); o[5] = bf16bits(v1[1]);
    o[6] = bf16bits(v1[2]); o[7] = bf16bits(v1[3]);
    return o;
}

// ---------------------------------------------------------------------------
// Prep (all regions vectorized, 8 elems/thread except cnt):
//   embB(40000t) W1b(20480t) W2b(8192t) aghT(32768t, transpose) W3b(10240t) cnt(10000t)
// ---------------------------------------------------------------------------
#define PV_EMB 320000
#define PV_W1  20480
#define PV_W2  8192
#define PV_AGH 32768
#define PV_W3  10240
#define PV_CNT 10000
#define PREP_TOTAL (PV_EMB + PV_W1 + PV_W2 + PV_AGH + PV_W3 + PV_CNT)
__global__ void prep_kernel(const float* __restrict__ emb,
                            const float* __restrict__ W1,
                            const float* __restrict__ W2,
                            const float* __restrict__ agh,
                            const float* __restrict__ W3,
                            __hip_bfloat16* __restrict__ embB,
                            __hip_bfloat16* __restrict__ W1b,
                            __hip_bfloat16* __restrict__ W2b,
                            __hip_bfloat16* __restrict__ aghT,
                            __hip_bfloat16* __restrict__ W3b,
                            int* __restrict__ cnt) {
    int tid = blockIdx.x * blockDim.x + threadIdx.x;
    if (tid >= PREP_TOTAL) return;
    int j = tid;
    if (j < PV_EMB) {
        int base = j * 8;
        *(short8*)((short*)embB + base) =
            cvt8(*(const f32x4*)(emb + base), *(const f32x4*)(emb + base + 4));
        return;
    }
    j -= PV_EMB;
    if (j < PV_W1) {
        int base = j * 8;
        *(short8*)((short*)W1b + base) =
            cvt8(*(const f32x4*)(W1 + base), *(const f32x4*)(W1 + base + 4));
        return;
    }
    j -= PV_W1;
    if (j < PV_W2) {
        int base = j * 8;
        *(short8*)((short*)W2b + base) =
            cvt8(*(const f32x4*)(W2 + base), *(const f32x4*)(W2 + base + 4));
        return;
    }
    j -= PV_W2;
    if (j < PV_AGH) {   // aghT[n][k0..k0+8] = agh[k][n], n = j>>5, k0 = (j&31)*8
        int n = j >> 5, k0 = (j & 31) * 8;
        short8 o;
#pragma unroll
        for (int i = 0; i < 8; ++i)
            o[i] = bf16bits(agh[(long long)(k0 + i) * 1024 + n]);
        *(short8*)((short*)aghT + n * 256 + k0) = o;
        return;
    }
    j -= PV_AGH;
    if (j < PV_W3) {   // W3b padded to 320x256; rows 0..257 valid (flat 66048 = 8256*8)
        int base = j * 8;
        if (j < 8256) {
            *(short8*)((short*)W3b + base) =
                cvt8(*(const f32x4*)(W3 + base), *(const f32x4*)(W3 + base + 4));
        } else {
            short8 z = {};
            *(short8*)((short*)W3b + base) = z;
        }
        return;
    }
    j -= PV_W3;
    cnt[j] = 0;
}

// ---------------------------------------------------------------------------
// Count-sort of pairs by destination atom: hist -> scan -> scatter_ids.
// ---------------------------------------------------------------------------
__global__ void hist_kernel(const int* __restrict__ idx_j, int* __restrict__ cnt) {
    int p = blockIdx.x * blockDim.x + threadIdx.x;
    if (p >= N_PAIRS) return;
    atomicAdd(&cnt[idx_j[p]], 1);
}

__global__ __launch_bounds__(1024) void scan_kernel(const int* __restrict__ cnt,
                                                    int* __restrict__ start,
                                                    int* __restrict__ cursor) {
    __shared__ int part[1024];
    int t = threadIdx.x;
    int base = t * 10;
    int pre[10];
    int sum = 0;
#pragma unroll
    for (int k = 0; k < 10; ++k) {
        int i = base + k;
        int v = (i < N_ATOMS) ? cnt[i] : 0;
        pre[k] = sum;
        sum += v;
    }
    part[t] = sum;
    __syncthreads();
    for (int off = 1; off < 1024; off <<= 1) {
        int v = (t >= off) ? part[t - off] : 0;
        __syncthreads();
        part[t] += v;
        __syncthreads();
    }
    int excl = (t == 0) ? 0 : part[t - 1];
#pragma unroll
    for (int k = 0; k < 10; ++k) {
        int i = base + k;
        if (i < N_ATOMS) {
            start[i]  = excl + pre[k];
            cursor[i] = excl + pre[k];
        }
    }
}

__global__ void scatter_ids_kernel(const int* __restrict__ idx_j,
                                   int* __restrict__ cursor,
                                   int* __restrict__ sorted) {
    int p = blockIdx.x * blockDim.x + threadIdx.x;
    if (p >= N_PAIRS) return;
    int i = idx_j[p];
    int pos = atomicAdd(&cursor[i], 1);
    sorted[pos] = p;
}

// ---------------------------------------------------------------------------
// bf16 MFMA GEMM (Mmat only): C[M,N] = A[M,K] @ B[N,K]^T, bf16 out.
// 64-thread blocks, one wave, 64x64 tile (4x4 frags). No LDS.
// ---------------------------------------------------------------------------
template<int M, int N, int K>
__global__ __launch_bounds__(64) void gemm_mfma(const short* __restrict__ A,
                                                const short* __restrict__ B,
                                                __hip_bfloat16* __restrict__ Cout) {
    int lane = threadIdx.x;
    int m0 = blockIdx.x * 64;
    int n0 = blockIdx.y * 64;
    int lr = lane & 15;
    int koff0 = (lane >> 4) * 8;

    f32x4 acc[4][4] = {};
    const short8 zero8 = {};

    const short* Arow[4];
    bool ok[4];
#pragma unroll
    for (int fm = 0; fm < 4; ++fm) {
        int row = m0 + fm * 16 + lr;
        ok[fm] = row < M;
        Arow[fm] = A + (long long)(ok[fm] ? row : 0) * K + koff0;
    }
    const short* Bb = B + (long long)(n0 + lr) * K + koff0;

#pragma unroll 2
    for (int ks = 0; ks < K; ks += 32) {
        short8 a[4], b[4];
#pragma unroll
        for (int fm = 0; fm < 4; ++fm)
            a[fm] = ok[fm] ? *(const short8*)(Arow[fm] + ks) : zero8;
#pragma unroll
        for (int fn = 0; fn < 4; ++fn)
            b[fn] = *(const short8*)(Bb + (long long)fn * 16 * K + ks);
#pragma unroll
        for (int fm = 0; fm < 4; ++fm)
#pragma unroll
            for (int fn = 0; fn < 4; ++fn)
                acc[fm][fn] = __builtin_amdgcn_mfma_f32_16x16x32_bf16(a[fm], b[fn],
                                                                      acc[fm][fn], 0, 0, 0);
    }

    int rbase = (lane >> 4) * 4;
#pragma unroll
    for (int fm = 0; fm < 4; ++fm) {
#pragma unroll
        for (int fn = 0; fn < 4; ++fn) {
            int col = n0 + fn * 16 + lr;
#pragma unroll
            for (int r = 0; r < 4; ++r) {
                int row = m0 + fm * 16 + rbase + r;
                if (row >= M) continue;
                Cout[(long long)row * N + col] = __float2bfloat16(acc[fm][fn][r]);
            }
        }
    }
}

// ---------------------------------------------------------------------------
// Fused gather + build_combined: 16 atoms per 256-thread block (grid 625).
// comb cols [576,640) are never read by the MLP (structurally zero) -> not written.
// ---------------------------------------------------------------------------
__global__ __launch_bounds__(256) void gather_build(
        const int* __restrict__ sorted,
        const int* __restrict__ start,
        const int* __restrict__ cnt,
        const float* __restrict__ gs,
        const float* __restrict__ gv,
        const float* __restrict__ emb,
        const float* __restrict__ q,
        const float* __restrict__ W_gs,
        const __hip_bfloat16* __restrict__ Mmat,
        __hip_bfloat16* __restrict__ combined) {
    __shared__ float sW[FDIM * 17];
    __shared__ float sG[16][GDIM];
    __shared__ float sGV[16][48];
    int i0 = blockIdx.x * 16;
    int t = threadIdx.x;

    for (int j = t; j < FDIM * GDIM; j += 256)
        sW[(j >> 4) * 17 + (j & 15)] = W_gs[j];

    // Phase A: gather (16 lanes per atom)
    {
        int grp = t >> 4, l = t & 15;
        int atom = i0 + grp;
        int s = start[atom], c = cnt[atom];
        const float* base;
        long long stride;
        if (l < 4) { base = gs + l * 4;        stride = 16; }
        else       { base = gv + (l - 4) * 4;  stride = 48; }
        f32x4 acc = {0.f, 0.f, 0.f, 0.f};
        int j = 0;
        for (; j + 1 < c; j += 2) {
            int p0 = sorted[s + j];
            int p1 = sorted[s + j + 1];
            acc += *(const f32x4*)(base + p0 * stride);
            acc += *(const f32x4*)(base + p1 * stride);
        }
        if (j < c) {
            int p0 = sorted[s + j];
            acc += *(const f32x4*)(base + p0 * stride);
        }
        if (l < 4) *(f32x4*)&sG[grp][l * 4] = acc;
        else       *(f32x4*)&sGV[grp][(l - 4) * 4] = acc;
    }
    __syncthreads();

    float wreg[GDIM];
#pragma unroll
    for (int g = 0; g < GDIM; ++g) wreg[g] = sW[t * 17 + g];

    // radial_emb / radial_q (thread t owns feature f = t)
#pragma unroll 4
    for (int a = 0; a < 16; ++a) {
        int i = i0 + a;
        float S = 0.f;
#pragma unroll
        for (int g = 0; g < GDIM; ++g) S += sG[a][g] * wreg[g];
        float ev = emb[(long long)i * FDIM + t];
        float qq = q[i];
        __hip_bfloat16* crow = combined + (long long)i * MLP_IN;
        crow[t]       = __float2bfloat16(ev * S);
        crow[320 + t] = __float2bfloat16(qq * S);
    }

    // vector_emb: wave w handles atoms w, w+4, w+8, w+12; lanes cover h=0..63
#pragma unroll
    for (int r = 0; r < 4; ++r) {
        int a = (t >> 6) + r * 4;
        int h = t & 63;
        int i = i0 + a;
        float a0 = 0.f, a1 = 0.f, a2 = 0.f;
#pragma unroll
        for (int g = 0; g < GDIM; ++g) {
            float mg = __bfloat162float(Mmat[(long long)i * 1024 + g * 64 + h]);
            a0 += mg * sGV[a][g];
            a1 += mg * sGV[a][16 + g];
            a2 += mg * sGV[a][32 + g];
        }
        __hip_bfloat16* crow = combined + (long long)i * MLP_IN;
        crow[256 + h] = __float2bfloat16(sqrtf(a0 * a0 + a1 * a1 + a2 * a2));
    }
}

// ---------------------------------------------------------------------------
// Fused MLP v3: 32 atoms per 512-thread block (8 waves), grid 313.
// Wave = 32 rows x 32 cols: per K-step 2 A-loads + 2 B-loads -> 4 MFMA
// (every load feeds 2 MFMAs). All 256 CUs get work (313 blocks, 2504 waves
// ~2.4/SIMD). Phase 1 K=576 (cols 576-639 of comb are structurally zero).
// h1/h2 in LDS (32x264 bf16 each = 33.8 KB). Phase 3: 20 col-frags, wave w
// -> frags {w, w+8, w+16(w<4)}. Last block: rows clamped on load, guarded
// on store.
// ---------------------------------------------------------------------------
__global__ __launch_bounds__(512) void mlp_fused(
        const short* __restrict__ comb,
        const short* __restrict__ W1b,
        const short* __restrict__ W2b,
        const short* __restrict__ W3b,
        const float* __restrict__ b1,
        const float* __restrict__ b2,
        const float* __restrict__ b3,
        float* __restrict__ outp) {
    __shared__ short h1s[32][264];
    __shared__ short h2s[32][264];
    int lane = threadIdx.x & 63;
    int wave = threadIdx.x >> 6;
    int m0 = blockIdx.x * 32;
    int lr = lane & 15;
    int ko = (lane >> 4) * 8;
    int rbase = (lane >> 4) * 4;

    // Clamped A-row pointers (rows >= N_ATOMS read row N_ATOMS-1; discarded at store)
    const short* Arow[2];
#pragma unroll
    for (int fm = 0; fm < 2; ++fm) {
        int row = m0 + fm * 16 + lr;
        if (row >= N_ATOMS) row = N_ATOMS - 1;
        Arow[fm] = comb + (long long)row * MLP_IN + ko;
    }

    // Phase 1: h1 = gelu(comb @ W1^T + b1); wave cols [32w, 32w+32), K=576
    {
        f32x4 acc[2][2] = {};
        const short* Bb = W1b + (long long)(wave * 32 + lr) * MLP_IN + ko;
#pragma unroll 3
        for (int ks = 0; ks < 576; ks += 32) {
            short8 a[2], b[2];
#pragma unroll
            for (int fm = 0; fm < 2; ++fm) a[fm] = *(const short8*)(Arow[fm] + ks);
#pragma unroll
            for (int fn = 0; fn < 2; ++fn)
                b[fn] = *(const short8*)(Bb + (long long)fn * 16 * MLP_IN + ks);
#pragma unroll
            for (int fm = 0; fm < 2; ++fm)
#pragma unroll
                for (int fn = 0; fn < 2; ++fn)
                    acc[fm][fn] = __builtin_amdgcn_mfma_f32_16x16x32_bf16(a[fm], b[fn],
                                                                          acc[fm][fn], 0, 0, 0);
        }
#pragma unroll
        for (int fn = 0; fn < 2; ++fn) {
            int col = wave * 32 + fn * 16 + lr;
            float bias = b1[col];
#pragma unroll
            for (int fm = 0; fm < 2; ++fm)
#pragma unroll
                for (int r = 0; r < 4; ++r)
                    h1s[fm * 16 + rbase + r][col] = bf16bits(gelu_exact(acc[fm][fn][r] + bias));
        }
    }
    __syncthreads();

    // Phase 2: h2 = gelu(h1 @ W2^T + b2); A from LDS
    {
        f32x4 acc[2][2] = {};
        const short* Bb = W2b + (long long)(wave * 32 + lr) * HIDDIM + ko;
#pragma unroll
        for (int ks = 0; ks < HIDDIM; ks += 32) {
            short8 a[2], b[2];
#pragma unroll
            for (int fm = 0; fm < 2; ++fm)
                a[fm] = *(const short8*)(&h1s[fm * 16 + lr][ko + ks]);
#pragma unroll
            for (int fn = 0; fn < 2; ++fn)
                b[fn] = *(const short8*)(Bb + (long long)fn * 16 * HIDDIM + ks);
#pragma unroll
            for (int fm = 0; fm < 2; ++fm)
#pragma unroll
                for (int fn = 0; fn < 2; ++fn)
                    acc[fm][fn] = __builtin_amdgcn_mfma_f32_16x16x32_bf16(a[fm], b[fn],
                                                                          acc[fm][fn], 0, 0, 0);
        }
#pragma unroll
        for (int fn = 0; fn < 2; ++fn) {
            int col = wave * 32 + fn * 16 + lr;
            float bias = b2[col];
#pragma unroll
            for (int fm = 0; fm < 2; ++fm)
#pragma unroll
                for (int r = 0; r < 4; ++r)
                    h2s[fm * 16 + rbase + r][col] = bf16bits(gelu_exact(acc[fm][fn][r] + bias));
        }
    }
    __syncthreads();

    // Phase 3: out = h2 @ W3^T + b3 (320 padded cols = 20 frags);
    // wave w -> frags w, w+8, and (w<4) w+16. Remap (delta_a | delta_q | f).
    {
        int f0 = wave, f1 = wave + 8, f2 = wave + 16;
        bool has2 = (wave < 4);
        f32x4 acc0[2] = {}, acc1[2] = {}, acc2[2] = {};
        const short* B0 = W3b + (long long)(f0 * 16 + lr) * HIDDIM + ko;
        const short* B1 = W3b + (long long)(f1 * 16 + lr) * HIDDIM + ko;
        const short* B2 = W3b + (long long)((has2 ? f2 : f0) * 16 + lr) * HIDDIM + ko;
#pragma unroll
        for (int ks = 0; ks < HIDDIM; ks += 32) {
            short8 a[2];
#pragma unroll
            for (int fm = 0; fm < 2; ++fm)
                a[fm] = *(const short8*)(&h2s[fm * 16 + lr][ko + ks]);
            short8 b0 = *(const short8*)(B0 + ks);
            short8 b1v = *(const short8*)(B1 + ks);
#pragma unroll
            for (int fm = 0; fm < 2; ++fm) {
                acc0[fm] = __builtin_amdgcn_mfma_f32_16x16x32_bf16(a[fm], b0, acc0[fm], 0, 0, 0);
                acc1[fm] = __builtin_amdgcn_mfma_f32_16x16x32_bf16(a[fm], b1v, acc1[fm], 0, 0, 0);
            }
            if (has2) {
                short8 b2v = *(const short8*)(B2 + ks);
#pragma unroll
                for (int fm = 0; fm < 2; ++fm)
                    acc2[fm] = __builtin_amdgcn_mfma_f32_16x16x32_bf16(a[fm], b2v, acc2[fm], 0, 0, 0);
            }
        }
#pragma unroll
        for (int slot = 0; slot < 3; ++slot) {
            if (slot == 2 && !has2) continue;
            int f = (slot == 0) ? f0 : (slot == 1) ? f1 : f2;
            int col = f * 16 + lr;
            if (col >= MLP_OUT) continue;
            float bias = b3[col];
#pragma unroll
            for (int fm = 0; fm < 2; ++fm) {
#pragma unroll
                for (int r = 0; r < 4; ++r) {
                    int row = m0 + fm * 16 + rbase + r;
                    if (row >= N_ATOMS) continue;
                    f32x4 av = (slot == 0) ? acc0[fm] : (slot == 1) ? acc1[fm] : acc2[fm];
                    float v = av[r] + bias;
                    if (col == 0)      outp[2560000 + row] = v;
                    else if (col == 1) outp[2570000 + row] = v;
                    else               outp[(long long)row * 256 + (col - 2)] = v;
                }
            }
        }
    }
}

extern "C" void kernel_launch(void* const* d_in, const int* in_sizes, int n_in,
                              void* d_out, int out_size, void* d_ws, size_t ws_size,
                              hipStream_t stream) {
    const float* emb  = (const float*)d_in[0];
    const float* q    = (const float*)d_in[1];
    const int*   pidx = (const int*)d_in[2];
    const float* gs   = (const float*)d_in[3];
    const float* gv   = (const float*)d_in[4];
    const float* agh  = (const float*)d_in[5];
    const float* W_gs = (const float*)d_in[6];
    const float* W1   = (const float*)d_in[7];
    const float* b1   = (const float*)d_in[8];
    const float* W2   = (const float*)d_in[9];
    const float* b2   = (const float*)d_in[10];
    const float* W3   = (const float*)d_in[11];
    const float* b3   = (const float*)d_in[12];
    float* out = (float*)d_out;
    float* ws  = (float*)d_ws;

    // Workspace (float-slot offsets). Peak 10,076,720 floats = 40.3 MB
    // (42.9 MB proven safe in r5; r4's 53.1 MB overflowed).
    int*   cnt    = (int*)(ws);                                // 10,000
    int*   startA = (int*)(ws + 10000);                        // 10,000
    int*   cursor = (int*)(ws + 20000);                        // 10,000
    int*   sorted = (int*)(ws + 30000);                        // 160,000
    __hip_bfloat16* Mmat = (__hip_bfloat16*)(ws + 190000);     // 10000x1024 bf16
    __hip_bfloat16* embB = (__hip_bfloat16*)(ws + 5310000);    // 10000x256 bf16
    __hip_bfloat16* aghT = (__hip_bfloat16*)(ws + 6590000);    // 1024x256 bf16
    __hip_bfloat16* W1b  = (__hip_bfloat16*)(ws + 6721072);    // 256x640 bf16
    __hip_bfloat16* W2b  = (__hip_bfloat16*)(ws + 6802992);    // 256x256 bf16
    __hip_bfloat16* W3b  = (__hip_bfloat16*)(ws + 6835760);    // 320x256 bf16 (padded)
    __hip_bfloat16* comb = (__hip_bfloat16*)(ws + 6876720);    // 10000x640 bf16
    // end: 10,076,720 floats

    const int* idx_j = pidx + N_PAIRS;

    {   // conversions + transposes + cnt zeroing (all vectorized)
        int blocks = (PREP_TOTAL + 255) / 256;
        prep_kernel<<<blocks, 256, 0, stream>>>(emb, W1, W2, agh, W3,
                                                embB, W1b, W2b, aghT, W3b, cnt);
    }
    {   // count-sort pairs by atom
        int blocks = (N_PAIRS + 255) / 256;
        hist_kernel<<<blocks, 256, 0, stream>>>(idx_j, cnt);
        scan_kernel<<<1, 1024, 0, stream>>>(cnt, startA, cursor);
        scatter_ids_kernel<<<blocks, 256, 0, stream>>>(idx_j, cursor, sorted);
    }
    {   // Mmat = embB @ aghT^T : (10000x256)@(256x1024) -> bf16
        dim3 grid((N_ATOMS + 63) / 64, 1024 / 64);
        gemm_mfma<N_ATOMS, 1024, 256><<<grid, 64, 0, stream>>>(
            (const short*)embB, (const short*)aghT, Mmat);
    }
    // fused gather + combined-builder (625 blocks)
    gather_build<<<(N_ATOMS + 15) / 16, 256, 0, stream>>>(
        sorted, startA, cnt, gs, gv, emb, q, W_gs, Mmat, comb);
    // fused 3-layer MLP + output remap (313 blocks x 512 thr)
    mlp_fused<<<(N_ATOMS + 31) / 32, 512, 0, stream>>>(
        (const short*)comb, (const short*)W1b, (const short*)W2b, (const short*)W3b,
        b1, b2, b3, out);
}